// Round 4
// baseline (2867.427 us; speedup 1.0000x reference)
//
#include <hip/hip_runtime.h>
#include <cstdint>
#include <cstddef>

typedef _Float16 f16;
typedef __attribute__((ext_vector_type(4))) _Float16 f16x4;
typedef __attribute__((ext_vector_type(8))) _Float16 f16x8;
typedef __attribute__((ext_vector_type(4))) float f32x4;

#define MFMA_F16(a, b, c) __builtin_amdgcn_mfma_f32_16x16x32_f16((a), (b), (c), 0, 0, 0)

static constexpr int BB   = 8;
static constexpr int SS   = 2048;
static constexpr int DD   = 1024;
static constexpr int HALF = 512;
static constexpr int T32  = 256 * 32;   // f16 elems per 256-row K-tile slot (16 KB)
static constexpr int T512 = 512 * 32;   // f16 elems per 512-row K-tile slot (32 KB)

// async global->LDS, 16 B per lane; LDS dest is wave-uniform base + lane*16.
__device__ __forceinline__ void gll16(const f16* g, f16* lds) {
  __builtin_amdgcn_global_load_lds(
      (__attribute__((address_space(1))) void*)(g),
      (__attribute__((address_space(3))) void*)(lds), 16, 0, 0);
}

// Bijective XCD-aware block remap (valid when nwg % 8 == 0).  Used for qk/pv
// where it gives each XCD one batch (z-chunk) -> K/Vt panels L2-resident.
// NOT used for proj: natural order keeps all (y,z)-copies of an A-tile on the
// same XCD (lin%8 == x%8), which the remap destroyed (FETCH 74->203 MB, R3).
__device__ __forceinline__ dim3 xcd_swz() {
  const int gx = gridDim.x, gy = gridDim.y;
  const int lin = blockIdx.x + gx * (blockIdx.y + gy * blockIdx.z);
  const int nwg = gx * gy * (int)gridDim.z;
  const int q = nwg >> 3;
  const int nlin = (lin & 7) * q + (lin >> 3);
  dim3 r;
  r.x = nlin % gx;
  const int rest = nlin / gx;
  r.y = rest % gy;
  r.z = rest / gy;
  return r;
}

// ---------------------------------------------------------------------------
// Fused prep: blocks [0,1024) convert W (fp32->fp16); blocks [1024,1024+16384)
// build Xh = concat(t_out,c_out) fp16 for ALL 8 batches.
// ---------------------------------------------------------------------------
__global__ __launch_bounds__(256) void fused_prep(
    const float* __restrict__ Wq, const float* __restrict__ Wk, const float* __restrict__ Wv,
    const float* __restrict__ t_out, const float* __restrict__ c_out,
    f16* __restrict__ Whq, f16* __restrict__ Whk, f16* __restrict__ Whv,
    f16* __restrict__ Xh)
{
  if (blockIdx.x < 1024) {
    const int i = (blockIdx.x * 256 + threadIdx.x) * 4;
    const float4 q = *(const float4*)(Wq + i);
    const float4 k = *(const float4*)(Wk + i);
    const float4 v = *(const float4*)(Wv + i);
    f16x4 a;
    a.x = (f16)q.x; a.y = (f16)q.y; a.z = (f16)q.z; a.w = (f16)q.w; *(f16x4*)(Whq + i) = a;
    a.x = (f16)k.x; a.y = (f16)k.y; a.z = (f16)k.z; a.w = (f16)k.w; *(f16x4*)(Whk + i) = a;
    a.x = (f16)v.x; a.y = (f16)v.y; a.z = (f16)v.z; a.w = (f16)v.w; *(f16x4*)(Whv + i) = a;
  } else {
    const size_t i = ((size_t)(blockIdx.x - 1024) * 256 + threadIdx.x) * 4;
    const int d = (int)(i & 1023);
    const size_t g = i >> 10;  // global token 0..16383
    const float* src = (d < HALF) ? (t_out + g * HALF + d)
                                  : (c_out + g * HALF + (d - HALF));
    const float4 x = *(const float4*)src;
    f16x4 h;
    h.x = (f16)x.x; h.y = (f16)x.y; h.z = (f16)x.z; h.w = (f16)x.w;
    *(f16x4*)(Xh + i) = h;
  }
}

// ===========================================================================
// proj_gemm: 512x512 tile, BK=32, 16 waves (1024 thr), wave C = 128x128.
// Rationale (R3 post-mortem): proj is staging-BYTES-bound; 512^2 halves the
// staged panel traffic (786 -> 393 MB).  Ring-2 LDS (2 x 32 KB x 2 ops =
// 128 KiB).  Tile-end vmcnt(0) drain is fine: the stage->wait window is the
// whole tile's compute (~5000 cyc) >> L3 latency.
// Swizzle: 16B granule g of row r lives at physical granule g ^ ((r>>1)&3);
// applied on the global SOURCE column (LDS dest linear, required by
// global_load_lds) and on the ds_read address (both-sides rule).
// Staging roles: waves 0-7 stage A (512 rows), waves 8-15 stage B.
// ===========================================================================
__device__ __forceinline__ void stage512(
    f16* slot, const f16* g, size_t r0, int ld, int k0, int wl, int rr, int gg)
{
#pragma unroll
  for (int i = 0; i < 4; ++i) {
    const int rb  = wl * 64 + i * 16;        // wave-uniform row block
    const int row = rb + rr;
    const int lg  = gg ^ ((row >> 1) & 3);   // pre-swizzled source granule
    gll16(g + (r0 + (size_t)row) * ld + k0 + lg * 8, slot + (size_t)rb * 32);
  }
}

__global__ __launch_bounds__(1024) void proj_gemm(
    const f16* __restrict__ Xh,
    const f16* __restrict__ Whq, const f16* __restrict__ Whk, const f16* __restrict__ Whv,
    const float* __restrict__ bq, const float* __restrict__ bk, const float* __restrict__ bv,
    f16* __restrict__ Q, f16* __restrict__ K, f16* __restrict__ Vv)
{
  __shared__ alignas(16) f16 As[2 * T512];
  __shared__ alignas(16) f16 Bs[2 * T512];

  const int z = blockIdx.z;
  const f16* Wh = (z == 0) ? Whq : (z == 1) ? Whk : Whv;
  const float* bias = (z == 0) ? bq : (z == 1) ? bk : bv;
  f16* dst = (z == 0) ? Q : (z == 1) ? K : Vv;

  const int t = threadIdx.x, lane = t & 63, wave = t >> 6;   // wave 0..15
  const int wm = wave >> 2, wn = wave & 3;                   // 4x4 wave grid
  const int col16 = lane & 15, quad = lane >> 4;
  const int m0 = blockIdx.x * 512, n0 = blockIdx.y * 512;

  // staging role: waves 0-7 -> A, 8-15 -> B
  const int wl = wave & 7, rr = lane >> 2, gg = lane & 3;
  const f16*  g_st = (wave < 8) ? Xh : Wh;
  const size_t r0_st = (wave < 8) ? (size_t)m0 : (size_t)n0;
  f16* ringp = (wave < 8) ? As : Bs;

  f32x4 acc[8][8];
#pragma unroll
  for (int i = 0; i < 8; ++i)
#pragma unroll
    for (int j = 0; j < 8; ++j) acc[i][j] = f32x4{0.f, 0.f, 0.f, 0.f};

  // prologue: tile 0
  stage512(ringp, g_st, r0_st, DD, 0, wl, rr, gg);
  asm volatile("s_waitcnt vmcnt(0)" ::: "memory");
  __builtin_amdgcn_s_barrier();

  for (int kt = 0; kt < DD / 32; ++kt) {
    const f16* At = As + (kt & 1) * T512;
    const f16* Bt = Bs + (kt & 1) * T512;
    f16* Sn = ringp + ((kt + 1) & 1) * T512;

    f16x8 a[4], b[8];

    // -------- phase 0: B frags (all 8) + A rows [0,64) ---------------------
#pragma unroll
    for (int j = 0; j < 8; ++j) {
      const int r = wn * 128 + j * 16 + col16;
      b[j] = *(const f16x8*)&Bt[r * 32 + ((quad ^ ((r >> 1) & 3)) << 3)];
    }
#pragma unroll
    for (int i = 0; i < 4; ++i) {
      const int r = wm * 128 + i * 16 + col16;
      a[i] = *(const f16x8*)&At[r * 32 + ((quad ^ ((r >> 1) & 3)) << 3)];
    }
    if (kt + 1 < DD / 32)
      stage512(Sn, g_st, r0_st, DD, (kt + 1) * 32, wl, rr, gg);
    __builtin_amdgcn_s_barrier();
    asm volatile("s_waitcnt lgkmcnt(0)" ::: "memory");
    __builtin_amdgcn_sched_barrier(0);
    __builtin_amdgcn_s_setprio(1);
#pragma unroll
    for (int i = 0; i < 4; ++i)
#pragma unroll
      for (int j = 0; j < 8; ++j)
        acc[i][j] = MFMA_F16(a[i], b[j], acc[i][j]);
    __builtin_amdgcn_s_setprio(0);
    __builtin_amdgcn_s_barrier();

    // -------- phase 1: A rows [64,128), reuse b[] --------------------------
#pragma unroll
    for (int i = 0; i < 4; ++i) {
      const int r = wm * 128 + 64 + i * 16 + col16;
      a[i] = *(const f16x8*)&At[r * 32 + ((quad ^ ((r >> 1) & 3)) << 3)];
    }
    __builtin_amdgcn_s_barrier();
    asm volatile("s_waitcnt lgkmcnt(0)" ::: "memory");
    __builtin_amdgcn_sched_barrier(0);
    __builtin_amdgcn_s_setprio(1);
#pragma unroll
    for (int i = 0; i < 4; ++i)
#pragma unroll
      for (int j = 0; j < 8; ++j)
        acc[i + 4][j] = MFMA_F16(a[i], b[j], acc[i + 4][j]);
    __builtin_amdgcn_s_setprio(0);

    // tile end: certify tile kt+1 landed; WAR-protect the slot we just read.
    asm volatile("s_waitcnt vmcnt(0)" ::: "memory");
    __builtin_amdgcn_s_barrier();
  }

  // epilogue
#pragma unroll
  for (int j = 0; j < 8; ++j) {
    const int gn = n0 + wn * 128 + j * 16 + col16;
    const float bb_ = bias[gn];
#pragma unroll
    for (int i = 0; i < 8; ++i) {
      const int gm = m0 + wm * 128 + i * 16 + quad * 4;
#pragma unroll
      for (int r = 0; r < 4; ++r)
        dst[(size_t)(gm + r) * DD + gn] = (f16)(acc[i][j][r] + bb_);
    }
  }
}

// ---------------------------------------------------------------------------
// 8-wave 256x256 pipeline (qk/pv), BK=32, ring-4, lead-3, m201-style phases.
// Unchanged from R3 (proven: 0 bank conflicts, correct ledger).
// ---------------------------------------------------------------------------
__device__ __forceinline__ void stage_half(
    f16* s, const f16* g, size_t r0, int ld, int k0, int u, int w4, int rr, int gg)
{
#pragma unroll
  for (int q = 0; q < 2; ++q) {
    const int rb  = u * 128 + w4 * 32 + q * 16;   // wave-uniform row block
    const int row = rb + rr;
    const int lg  = gg ^ ((row >> 1) & 3);        // pre-swizzled source granule
    gll16(g + (r0 + (size_t)row) * ld + k0 + lg * 8, s + (size_t)rb * 32);
  }
}

template <int K>
__device__ __forceinline__ void mma_pipeline(
    const f16* __restrict__ A, const f16* __restrict__ B,
    int lda, int ldb, size_t arow0, size_t brow0,
    f16* As, f16* Bs, f32x4 acc[8][4],
    int wave, int lane, int wm, int wn, int col16, int quad)
{
  constexpr int NT = K / 32;
  const int w4 = wave & 3, rr = lane >> 2, gg = lane & 3;
  const f16*  g_st  = (wave < 4) ? A : B;
  const size_t r0_st = (wave < 4) ? arow0 : brow0;
  const int    ld_st = (wave < 4) ? lda : ldb;
  f16*         ring  = (wave < 4) ? As : Bs;

#pragma unroll
  for (int pt = 0; pt < 3; ++pt)
#pragma unroll
    for (int u = 0; u < 2; ++u)
      stage_half(ring + pt * T32, g_st, r0_st, ld_st, pt * 32, u, w4, rr, gg);
  asm volatile("s_waitcnt vmcnt(8)" ::: "memory");
  __builtin_amdgcn_s_barrier();

  for (int t = 0; t < NT; ++t) {
    const f16* At = As + (t & 3) * T32;
    const f16* Bt = Bs + (t & 3) * T32;
    f16* Sn = ring + ((t + 3) & 3) * T32;
    const bool st = (t + 3 < NT);
    const int kn = (t + 3) * 32;

    f16x8 a[4], b[4];

    // ---------------- phase 0 ---------------------------------------------
#pragma unroll
    for (int j = 0; j < 4; ++j) {
      const int r = wn * 64 + j * 16 + col16;
      b[j] = *(const f16x8*)&Bt[r * 32 + ((quad ^ ((r >> 1) & 3)) << 3)];
    }
#pragma unroll
    for (int i = 0; i < 4; ++i) {
      const int r = wm * 128 + i * 16 + col16;
      a[i] = *(const f16x8*)&At[r * 32 + ((quad ^ ((r >> 1) & 3)) << 3)];
    }
    if (st) stage_half(Sn, g_st, r0_st, ld_st, kn, 0, w4, rr, gg);
    if (t < NT - 3)       asm volatile("s_waitcnt vmcnt(6)" ::: "memory");
    else if (t == NT - 3) asm volatile("s_waitcnt vmcnt(4)" ::: "memory");
    else                  asm volatile("s_waitcnt vmcnt(0)" ::: "memory");
    __builtin_amdgcn_s_barrier();
    asm volatile("s_waitcnt lgkmcnt(0)" ::: "memory");
    __builtin_amdgcn_sched_barrier(0);
    __builtin_amdgcn_s_setprio(1);
#pragma unroll
    for (int i = 0; i < 4; ++i)
#pragma unroll
      for (int j = 0; j < 4; ++j)
        acc[i][j] = MFMA_F16(a[i], b[j], acc[i][j]);
    __builtin_amdgcn_s_setprio(0);
    __builtin_amdgcn_s_barrier();

    // ---------------- phase 1 ---------------------------------------------
#pragma unroll
    for (int i = 0; i < 4; ++i) {
      const int r = wm * 128 + 64 + i * 16 + col16;
      a[i] = *(const f16x8*)&At[r * 32 + ((quad ^ ((r >> 1) & 3)) << 3)];
    }
    if (st) stage_half(Sn, g_st, r0_st, ld_st, kn, 1, w4, rr, gg);
    __builtin_amdgcn_s_barrier();
    asm volatile("s_waitcnt lgkmcnt(0)" ::: "memory");
    __builtin_amdgcn_sched_barrier(0);
    __builtin_amdgcn_s_setprio(1);
#pragma unroll
    for (int i = 0; i < 4; ++i)
#pragma unroll
      for (int j = 0; j < 4; ++j)
        acc[i + 4][j] = MFMA_F16(a[i], b[j], acc[i + 4][j]);
    __builtin_amdgcn_s_setprio(0);
    __builtin_amdgcn_s_barrier();
  }
}

// ---------------------------------------------------------------------------
// Transpose V [b][s][e] -> Vt [b][e][s], full batch (grid 32,16,8)
// ---------------------------------------------------------------------------
__global__ __launch_bounds__(256) void transpose_v(
    const f16* __restrict__ Vv, f16* __restrict__ Vt)
{
  __shared__ alignas(16) f16 tile[64][72];
  const int b  = blockIdx.z;
  const int s0 = blockIdx.x * 64;
  const int e0 = blockIdx.y * 64;
  const int t  = threadIdx.x;
  const int r  = t >> 3;
  const int c8 = (t & 7) * 8;

  const f16* src0 = Vv + ((size_t)(b * SS + s0 + r)) * DD + e0 + c8;
  const f16* src1 = Vv + ((size_t)(b * SS + s0 + r + 32)) * DD + e0 + c8;
  *(int4*)&tile[r][c8]      = *(const int4*)src0;
  *(int4*)&tile[r + 32][c8] = *(const int4*)src1;
  __syncthreads();

  f16x8 v0, v1;
#pragma unroll
  for (int u = 0; u < 8; ++u) {
    v0[u] = tile[c8 + u][r];
    v1[u] = tile[c8 + u][r + 32];
  }
  f16* dst0 = Vt + ((size_t)b * DD + e0 + r) * SS + s0 + c8;
  f16* dst1 = Vt + ((size_t)b * DD + e0 + r + 32) * SS + s0 + c8;
  *(f16x8*)dst0 = v0;
  *(f16x8*)dst1 = v1;
}

// ---------------------------------------------------------------------------
// Scores for chunk [b0, b0+c): grid (8, 8, c), 256x256 tiles.
// ---------------------------------------------------------------------------
__global__ __launch_bounds__(512, 2) void qk_gemm(
    const f16* __restrict__ Q, const f16* __restrict__ K, f16* __restrict__ Sc,
    int b0)
{
  __shared__ alignas(16) f16 As[4 * T32];
  __shared__ alignas(16) f16 Bs[4 * T32];

  const dim3 bid = xcd_swz();
  const int bb = bid.z;
  const int t = threadIdx.x, lane = t & 63, wave = t >> 6;
  const int wm = wave >> 2, wn = wave & 3, col16 = lane & 15, quad = lane >> 4;
  const int m0 = bid.y * 256, n0 = bid.x * 256;

  const size_t arow0 = (size_t)(b0 + bb) * SS + m0;
  const size_t brow0 = (size_t)(b0 + bb) * SS + n0;

  f32x4 acc[8][4];
#pragma unroll
  for (int i = 0; i < 8; ++i)
#pragma unroll
    for (int j = 0; j < 4; ++j) acc[i][j] = f32x4{0.f, 0.f, 0.f, 0.f};

  mma_pipeline<DD>(Q, K, DD, DD, arow0, brow0,
                   As, Bs, acc, wave, lane, wm, wn, col16, quad);

#pragma unroll
  for (int i = 0; i < 8; ++i)
#pragma unroll
    for (int j = 0; j < 4; ++j)
#pragma unroll
      for (int r = 0; r < 4; ++r) {
        const int gm = m0 + wm * 128 + i * 16 + quad * 4 + r;
        const int gn = n0 + wn * 64 + j * 16 + col16;
        Sc[((size_t)bb * SS + gm) * SS + gn] = (f16)acc[i][j][r];
      }
}

// ---------------------------------------------------------------------------
// Row softmax fp16 -> fp16, in place (row = 2048 f16; 256 thr x f16x8).
// ---------------------------------------------------------------------------
__global__ __launch_bounds__(256) void softmax_rows(f16* __restrict__ Sc)
{
  const size_t row = blockIdx.x;
  f16* p = Sc + row * SS;
  const int t = threadIdx.x;

  const f16x8 v = *(const f16x8*)(p + t * 8);
  float xs[8];
#pragma unroll
  for (int u = 0; u < 8; ++u) xs[u] = (float)v[u];

  float m = xs[0];
#pragma unroll
  for (int u = 1; u < 8; ++u) m = fmaxf(m, xs[u]);
#pragma unroll
  for (int off = 32; off > 0; off >>= 1) m = fmaxf(m, __shfl_xor(m, off));
  __shared__ float redm[4];
  __shared__ float reds[4];
  if ((t & 63) == 0) redm[t >> 6] = m;
  __syncthreads();
  m = fmaxf(fmaxf(redm[0], redm[1]), fmaxf(redm[2], redm[3]));

  float e[8];
  float s = 0.f;
#pragma unroll
  for (int u = 0; u < 8; ++u) {
    e[u] = expf(xs[u] - m);
    s += e[u];
  }
#pragma unroll
  for (int off = 32; off > 0; off >>= 1) s += __shfl_xor(s, off);
  if ((t & 63) == 0) reds[t >> 6] = s;
  __syncthreads();
  s = reds[0] + reds[1] + reds[2] + reds[3];
  const float inv = 1.0f / s;

  f16x8 o;
#pragma unroll
  for (int u = 0; u < 8; ++u) o[u] = (f16)(e[u] * inv);
  *(f16x8*)(p + t * 8) = o;
}

// ---------------------------------------------------------------------------
// Output: out[(b0+bb)][s][e] = sum_j P[bb][s][j] * Vt[b0+bb][e][j]
// grid (4, 8, c), 256x256 tiles, K = SS = 2048.
// ---------------------------------------------------------------------------
__global__ __launch_bounds__(512, 2) void pv_gemm(
    const f16* __restrict__ P, const f16* __restrict__ Vt, float* __restrict__ out,
    int b0)
{
  __shared__ alignas(16) f16 As[4 * T32];
  __shared__ alignas(16) f16 Bs[4 * T32];

  const dim3 bid = xcd_swz();
  const int bb = bid.z;
  const int t = threadIdx.x, lane = t & 63, wave = t >> 6;
  const int wm = wave >> 2, wn = wave & 3, col16 = lane & 15, quad = lane >> 4;
  const int m0 = bid.y * 256;  // s
  const int n0 = bid.x * 256;  // e

  const size_t arow0 = (size_t)bb * SS + m0;         // P rows (pitch SS)
  const size_t brow0 = (size_t)(b0 + bb) * DD + n0;  // Vt rows (pitch SS)

  f32x4 acc[8][4];
#pragma unroll
  for (int i = 0; i < 8; ++i)
#pragma unroll
    for (int j = 0; j < 4; ++j) acc[i][j] = f32x4{0.f, 0.f, 0.f, 0.f};

  mma_pipeline<SS>(P, Vt, SS, SS, arow0, brow0,
                   As, Bs, acc, wave, lane, wm, wn, col16, quad);

#pragma unroll
  for (int i = 0; i < 8; ++i)
#pragma unroll
    for (int j = 0; j < 4; ++j)
#pragma unroll
      for (int r = 0; r < 4; ++r) {
        const int gm = m0 + wm * 128 + i * 16 + quad * 4 + r;
        const int gn = n0 + wn * 64 + j * 16 + col16;
        out[((size_t)(b0 + bb) * SS + gm) * DD + gn] = acc[i][j][r];
      }
}

// ---------------------------------------------------------------------------
extern "C" void kernel_launch(void* const* d_in, const int* in_sizes, int n_in,
                              void* d_out, int out_size, void* d_ws, size_t ws_size,
                              hipStream_t stream)
{
  const float* t_out = (const float*)d_in[0];
  const float* c_out = (const float*)d_in[1];
  const float* Wq    = (const float*)d_in[2];
  const float* bq    = (const float*)d_in[3];
  const float* Wk    = (const float*)d_in[4];
  const float* bk    = (const float*)d_in[5];
  const float* Wv    = (const float*)d_in[6];
  const float* bv    = (const float*)d_in[7];
  float* out = (float*)d_out;

  // ---- sizes ----
  const size_t WELT  = (size_t)DD * DD;
  const size_t TD8   = (size_t)BB * SS * DD;             // 16.7M elems
  const size_t XH_B  = TD8 * sizeof(f16);                // 33.55 MB
  const size_t SC1_B = (size_t)SS * SS * sizeof(f16);    // 8.39 MB per batch

  // ---- pick Sc chunk c (pure function of ws_size -> graph-safe) ----
  const size_t FIXED = 3 * WELT * sizeof(f16) + 4 * XH_B;  // 140.5 MB
  int c = 2;
  for (int cand : {8, 4}) {
    size_t xsc = (size_t)cand * SC1_B;
    if (xsc < XH_B) xsc = XH_B;
    if (FIXED + xsc <= ws_size) { c = cand; break; }
  }
  size_t xsc_bytes = (size_t)c * SC1_B;
  if (xsc_bytes < XH_B) xsc_bytes = XH_B;

  // ---- layout: [W][Xh|Sc(alias)][Q][K][Vv][Vt] ----
  char* ws = (char*)d_ws;
  f16* Whq = (f16*)ws;
  f16* Whk = Whq + WELT;
  f16* Whv = Whk + WELT;
  char* XSc = (char*)(Whv + WELT);
  f16* Xh = (f16*)XSc;     // live during prep/proj
  f16* Sc = (f16*)XSc;     // live during attention chunks (aliases Xh)
  f16* Q  = (f16*)(XSc + xsc_bytes);
  f16* K  = Q  + TD8;
  f16* Vv = K  + TD8;
  f16* Vt = Vv + TD8;

  fused_prep<<<dim3(1024 + 16384), dim3(256), 0, stream>>>(
      Wq, Wk, Wv, t_out, c_out, Whq, Whk, Whv, Xh);
  proj_gemm<<<dim3(32, 2, 3), dim3(1024), 0, stream>>>(
      Xh, Whq, Whk, Whv, bq, bk, bv, Q, K, Vv);
  transpose_v<<<dim3(32, 16, 8), dim3(256), 0, stream>>>(Vv, Vt);

  for (int b0 = 0; b0 < BB; b0 += c) {
    qk_gemm<<<dim3(8, 8, c), dim3(512), 0, stream>>>(Q, K, Sc, b0);
    softmax_rows<<<dim3(c * SS), dim3(256), 0, stream>>>(Sc);
    pv_gemm<<<dim3(4, 8, c), dim3(512), 0, stream>>>(Sc, Vt, out, b0);
  }
}

// Round 5
// 430.832 us; speedup vs baseline: 6.6556x; 6.6556x over previous
//
#include <hip/hip_runtime.h>
#include <cstdint>
#include <cstddef>

typedef _Float16 f16;
typedef __attribute__((ext_vector_type(4))) _Float16 f16x4;
typedef __attribute__((ext_vector_type(8))) _Float16 f16x8;
typedef __attribute__((ext_vector_type(4))) float f32x4;

#define MFMA_F16(a, b, c) __builtin_amdgcn_mfma_f32_16x16x32_f16((a), (b), (c), 0, 0, 0)

static constexpr int BB   = 8;
static constexpr int SS   = 2048;
static constexpr int DD   = 1024;
static constexpr int HALF = 512;
static constexpr int T32  = 256 * 32;   // f16 elems per K-tile slot (16 KB)

// async global->LDS, 16 B per lane; LDS dest is wave-uniform base + lane*16.
__device__ __forceinline__ void gll16(const f16* g, f16* lds) {
  __builtin_amdgcn_global_load_lds(
      (__attribute__((address_space(1))) void*)(g),
      (__attribute__((address_space(3))) void*)(lds), 16, 0, 0);
}

// Bijective XCD-aware block remap (valid when nwg % 8 == 0).  Used ONLY for
// qk/pv, where z-chunking gives each XCD one batch -> K/Vt panels L2-resident.
// NOT for proj: natural order already co-locates all 12 consumers of an
// A-tile on one XCD (lin = x + 64y + 256z, 64 == 0 mod 8); the remap broke
// that (FETCH 74 -> 203 MB, R3 post-mortem).
__device__ __forceinline__ dim3 xcd_swz() {
  const int gx = gridDim.x, gy = gridDim.y;
  const int lin = blockIdx.x + gx * (blockIdx.y + gy * blockIdx.z);
  const int nwg = gx * gy * (int)gridDim.z;
  const int q = nwg >> 3;
  const int nlin = (lin & 7) * q + (lin >> 3);
  dim3 r;
  r.x = nlin % gx;
  const int rest = nlin / gx;
  r.y = rest % gy;
  r.z = rest / gy;
  return r;
}

// ---------------------------------------------------------------------------
// Fused prep: blocks [0,1024) convert W (fp32->fp16); blocks [1024,1024+16384)
// build Xh = concat(t_out,c_out) fp16 for ALL 8 batches.
// ---------------------------------------------------------------------------
__global__ __launch_bounds__(256) void fused_prep(
    const float* __restrict__ Wq, const float* __restrict__ Wk, const float* __restrict__ Wv,
    const float* __restrict__ t_out, const float* __restrict__ c_out,
    f16* __restrict__ Whq, f16* __restrict__ Whk, f16* __restrict__ Whv,
    f16* __restrict__ Xh)
{
  if (blockIdx.x < 1024) {
    const int i = (blockIdx.x * 256 + threadIdx.x) * 4;
    const float4 q = *(const float4*)(Wq + i);
    const float4 k = *(const float4*)(Wk + i);
    const float4 v = *(const float4*)(Wv + i);
    f16x4 a;
    a.x = (f16)q.x; a.y = (f16)q.y; a.z = (f16)q.z; a.w = (f16)q.w; *(f16x4*)(Whq + i) = a;
    a.x = (f16)k.x; a.y = (f16)k.y; a.z = (f16)k.z; a.w = (f16)k.w; *(f16x4*)(Whk + i) = a;
    a.x = (f16)v.x; a.y = (f16)v.y; a.z = (f16)v.z; a.w = (f16)v.w; *(f16x4*)(Whv + i) = a;
  } else {
    const size_t i = ((size_t)(blockIdx.x - 1024) * 256 + threadIdx.x) * 4;
    const int d = (int)(i & 1023);
    const size_t g = i >> 10;  // global token 0..16383
    const float* src = (d < HALF) ? (t_out + g * HALF + d)
                                  : (c_out + g * HALF + (d - HALF));
    const float4 x = *(const float4*)src;
    f16x4 h;
    h.x = (f16)x.x; h.y = (f16)x.y; h.z = (f16)x.z; h.w = (f16)x.w;
    *(f16x4*)(Xh + i) = h;
  }
}

// ---------------------------------------------------------------------------
// 256x256 GEMM, BK=32, 8 waves (512 thr), wave C = 128x64, m201-style phases.
// LDS: ring of 4 K-tile slots per operand ([256][32] f16, 16 KB) = 128 KiB.
// Swizzle: 16B granule g of row r lives at physical granule g ^ ((r>>1)&3);
// applied on the global SOURCE column (LDS dest linear, required by
// global_load_lds) and on the ds_read address (both-sides rule).
//
// Phase = { ds_read subtile; stage 2 gll; [vmcnt at p0]; s_barrier;
//           lgkmcnt(0); sched_barrier; setprio(1); 16 MFMA; setprio(0);
//           s_barrier }.
// vmcnt ledger (4 gll per wave per tile, stage lead = 3 tiles):
//   at tile t phase 0 after staging: outstanding = t+1(4)+t+2(4)+t+3h0(2)=10;
//   vmcnt(6) retires exactly tile t+1 -> certified one tile EARLY, so the
//   pre-barrier ds_reads of tile t+1 at its phase 0 are race-free.
//   Tail: t==NT-3 -> vmcnt(4); t>=NT-2 -> vmcnt(0).
// WAR: stage at tile t targets slot (t+3)&3 == (t-1)&3 whose readers all
// passed tile t-1 phase-1's closing barrier.
//
// VGPR rule (R4 post-mortem): 512-thr blocks -> 2 waves/SIMD -> 256 VGPR cap;
// acc[8][4]=128 + frags fits.  1024-thr blocks cap at 128 VGPR -> spill.
// ---------------------------------------------------------------------------
__device__ __forceinline__ void stage_half(
    f16* s, const f16* g, size_t r0, int ld, int k0, int u, int w4, int rr, int gg)
{
#pragma unroll
  for (int q = 0; q < 2; ++q) {
    const int rb  = u * 128 + w4 * 32 + q * 16;   // wave-uniform row block
    const int row = rb + rr;
    const int lg  = gg ^ ((row >> 1) & 3);        // pre-swizzled source granule
    gll16(g + (r0 + (size_t)row) * ld + k0 + lg * 8, s + (size_t)rb * 32);
  }
}

template <int K>
__device__ __forceinline__ void mma_pipeline(
    const f16* __restrict__ A, const f16* __restrict__ B,
    int lda, int ldb, size_t arow0, size_t brow0,
    f16* As, f16* Bs, f32x4 acc[8][4],
    int wave, int lane, int wm, int wn, int col16, int quad)
{
  constexpr int NT = K / 32;
  const int w4 = wave & 3, rr = lane >> 2, gg = lane & 3;
  const f16*  g_st  = (wave < 4) ? A : B;
  const size_t r0_st = (wave < 4) ? arow0 : brow0;
  const int    ld_st = (wave < 4) ? lda : ldb;
  f16*         ring  = (wave < 4) ? As : Bs;

#pragma unroll
  for (int pt = 0; pt < 3; ++pt)
#pragma unroll
    for (int u = 0; u < 2; ++u)
      stage_half(ring + pt * T32, g_st, r0_st, ld_st, pt * 32, u, w4, rr, gg);
  asm volatile("s_waitcnt vmcnt(8)" ::: "memory");
  __builtin_amdgcn_s_barrier();

  for (int t = 0; t < NT; ++t) {
    const f16* At = As + (t & 3) * T32;
    const f16* Bt = Bs + (t & 3) * T32;
    f16* Sn = ring + ((t + 3) & 3) * T32;
    const bool st = (t + 3 < NT);
    const int kn = (t + 3) * 32;

    f16x8 a[4], b[4];

    // ---------------- phase 0 ---------------------------------------------
#pragma unroll
    for (int j = 0; j < 4; ++j) {
      const int r = wn * 64 + j * 16 + col16;
      b[j] = *(const f16x8*)&Bt[r * 32 + ((quad ^ ((r >> 1) & 3)) << 3)];
    }
#pragma unroll
    for (int i = 0; i < 4; ++i) {
      const int r = wm * 128 + i * 16 + col16;
      a[i] = *(const f16x8*)&At[r * 32 + ((quad ^ ((r >> 1) & 3)) << 3)];
    }
    if (st) stage_half(Sn, g_st, r0_st, ld_st, kn, 0, w4, rr, gg);
    if (t < NT - 3)       asm volatile("s_waitcnt vmcnt(6)" ::: "memory");
    else if (t == NT - 3) asm volatile("s_waitcnt vmcnt(4)" ::: "memory");
    else                  asm volatile("s_waitcnt vmcnt(0)" ::: "memory");
    __builtin_amdgcn_s_barrier();
    asm volatile("s_waitcnt lgkmcnt(0)" ::: "memory");
    __builtin_amdgcn_sched_barrier(0);
    __builtin_amdgcn_s_setprio(1);
#pragma unroll
    for (int i = 0; i < 4; ++i)
#pragma unroll
      for (int j = 0; j < 4; ++j)
        acc[i][j] = MFMA_F16(a[i], b[j], acc[i][j]);
    __builtin_amdgcn_s_setprio(0);
    __builtin_amdgcn_s_barrier();

    // ---------------- phase 1 ---------------------------------------------
#pragma unroll
    for (int i = 0; i < 4; ++i) {
      const int r = wm * 128 + 64 + i * 16 + col16;
      a[i] = *(const f16x8*)&At[r * 32 + ((quad ^ ((r >> 1) & 3)) << 3)];
    }
    if (st) stage_half(Sn, g_st, r0_st, ld_st, kn, 1, w4, rr, gg);
    __builtin_amdgcn_s_barrier();
    asm volatile("s_waitcnt lgkmcnt(0)" ::: "memory");
    __builtin_amdgcn_sched_barrier(0);
    __builtin_amdgcn_s_setprio(1);
#pragma unroll
    for (int i = 0; i < 4; ++i)
#pragma unroll
      for (int j = 0; j < 4; ++j)
        acc[i + 4][j] = MFMA_F16(a[i], b[j], acc[i + 4][j]);
    __builtin_amdgcn_s_setprio(0);
    __builtin_amdgcn_s_barrier();
  }
}

// ---------------------------------------------------------------------------
// QKV projection. grid (64, 4, 3): x = m-tile, y = n-tile, z = Q/K/V.
// NATURAL block order (see xcd_swz comment).
// ---------------------------------------------------------------------------
__global__ __launch_bounds__(512, 2) void proj_gemm(
    const f16* __restrict__ Xh,
    const f16* __restrict__ Whq, const f16* __restrict__ Whk, const f16* __restrict__ Whv,
    const float* __restrict__ bq, const float* __restrict__ bk, const float* __restrict__ bv,
    f16* __restrict__ Q, f16* __restrict__ K, f16* __restrict__ Vv)
{
  __shared__ alignas(16) f16 As[4 * T32];
  __shared__ alignas(16) f16 Bs[4 * T32];

  const int z = blockIdx.z;
  const f16* Wh = (z == 0) ? Whq : (z == 1) ? Whk : Whv;
  const float* bias = (z == 0) ? bq : (z == 1) ? bk : bv;
  f16* dst = (z == 0) ? Q : (z == 1) ? K : Vv;

  const int t = threadIdx.x, lane = t & 63, wave = t >> 6;
  const int wm = wave >> 2, wn = wave & 3, col16 = lane & 15, quad = lane >> 4;
  const int m0 = blockIdx.x * 256, n0 = blockIdx.y * 256;

  f32x4 acc[8][4];
#pragma unroll
  for (int i = 0; i < 8; ++i)
#pragma unroll
    for (int j = 0; j < 4; ++j) acc[i][j] = f32x4{0.f, 0.f, 0.f, 0.f};

  mma_pipeline<DD>(Xh, Wh, DD, DD, (size_t)m0, (size_t)n0,
                   As, Bs, acc, wave, lane, wm, wn, col16, quad);

#pragma unroll
  for (int j = 0; j < 4; ++j) {
    const int gn = n0 + wn * 64 + j * 16 + col16;
    const float bb_ = bias[gn];
#pragma unroll
    for (int i = 0; i < 8; ++i) {
      const int gm = m0 + wm * 128 + i * 16 + quad * 4;
#pragma unroll
      for (int r = 0; r < 4; ++r)
        dst[(size_t)(gm + r) * DD + gn] = (f16)(acc[i][j][r] + bb_);
    }
  }
}

// ---------------------------------------------------------------------------
// Transpose V [b][s][e] -> Vt [b][e][s], full batch (grid 32,16,8)
// ---------------------------------------------------------------------------
__global__ __launch_bounds__(256) void transpose_v(
    const f16* __restrict__ Vv, f16* __restrict__ Vt)
{
  __shared__ alignas(16) f16 tile[64][72];
  const int b  = blockIdx.z;
  const int s0 = blockIdx.x * 64;
  const int e0 = blockIdx.y * 64;
  const int t  = threadIdx.x;
  const int r  = t >> 3;
  const int c8 = (t & 7) * 8;

  const f16* src0 = Vv + ((size_t)(b * SS + s0 + r)) * DD + e0 + c8;
  const f16* src1 = Vv + ((size_t)(b * SS + s0 + r + 32)) * DD + e0 + c8;
  *(int4*)&tile[r][c8]      = *(const int4*)src0;
  *(int4*)&tile[r + 32][c8] = *(const int4*)src1;
  __syncthreads();

  f16x8 v0, v1;
#pragma unroll
  for (int u = 0; u < 8; ++u) {
    v0[u] = tile[c8 + u][r];
    v1[u] = tile[c8 + u][r + 32];
  }
  f16* dst0 = Vt + ((size_t)b * DD + e0 + r) * SS + s0 + c8;
  f16* dst1 = Vt + ((size_t)b * DD + e0 + r + 32) * SS + s0 + c8;
  *(f16x8*)dst0 = v0;
  *(f16x8*)dst1 = v1;
}

// ---------------------------------------------------------------------------
// Scores for chunk [b0, b0+c): grid (8, 8, c), 256x256 tiles.
// ---------------------------------------------------------------------------
__global__ __launch_bounds__(512, 2) void qk_gemm(
    const f16* __restrict__ Q, const f16* __restrict__ K, f16* __restrict__ Sc,
    int b0)
{
  __shared__ alignas(16) f16 As[4 * T32];
  __shared__ alignas(16) f16 Bs[4 * T32];

  const dim3 bid = xcd_swz();
  const int bb = bid.z;
  const int t = threadIdx.x, lane = t & 63, wave = t >> 6;
  const int wm = wave >> 2, wn = wave & 3, col16 = lane & 15, quad = lane >> 4;
  const int m0 = bid.y * 256, n0 = bid.x * 256;

  const size_t arow0 = (size_t)(b0 + bb) * SS + m0;
  const size_t brow0 = (size_t)(b0 + bb) * SS + n0;

  f32x4 acc[8][4];
#pragma unroll
  for (int i = 0; i < 8; ++i)
#pragma unroll
    for (int j = 0; j < 4; ++j) acc[i][j] = f32x4{0.f, 0.f, 0.f, 0.f};

  mma_pipeline<DD>(Q, K, DD, DD, arow0, brow0,
                   As, Bs, acc, wave, lane, wm, wn, col16, quad);

#pragma unroll
  for (int i = 0; i < 8; ++i)
#pragma unroll
    for (int j = 0; j < 4; ++j)
#pragma unroll
      for (int r = 0; r < 4; ++r) {
        const int gm = m0 + wm * 128 + i * 16 + quad * 4 + r;
        const int gn = n0 + wn * 64 + j * 16 + col16;
        Sc[((size_t)bb * SS + gm) * SS + gn] = (f16)acc[i][j][r];
      }
}

// ---------------------------------------------------------------------------
// Row softmax fp16 -> fp16, in place (row = 2048 f16; 256 thr x f16x8).
// ---------------------------------------------------------------------------
__global__ __launch_bounds__(256) void softmax_rows(f16* __restrict__ Sc)
{
  const size_t row = blockIdx.x;
  f16* p = Sc + row * SS;
  const int t = threadIdx.x;

  const f16x8 v = *(const f16x8*)(p + t * 8);
  float xs[8];
#pragma unroll
  for (int u = 0; u < 8; ++u) xs[u] = (float)v[u];

  float m = xs[0];
#pragma unroll
  for (int u = 1; u < 8; ++u) m = fmaxf(m, xs[u]);
#pragma unroll
  for (int off = 32; off > 0; off >>= 1) m = fmaxf(m, __shfl_xor(m, off));
  __shared__ float redm[4];
  __shared__ float reds[4];
  if ((t & 63) == 0) redm[t >> 6] = m;
  __syncthreads();
  m = fmaxf(fmaxf(redm[0], redm[1]), fmaxf(redm[2], redm[3]));

  float e[8];
  float s = 0.f;
#pragma unroll
  for (int u = 0; u < 8; ++u) {
    e[u] = expf(xs[u] - m);
    s += e[u];
  }
#pragma unroll
  for (int off = 32; off > 0; off >>= 1) s += __shfl_xor(s, off);
  if ((t & 63) == 0) reds[t >> 6] = s;
  __syncthreads();
  s = reds[0] + reds[1] + reds[2] + reds[3];
  const float inv = 1.0f / s;

  f16x8 o;
#pragma unroll
  for (int u = 0; u < 8; ++u) o[u] = (f16)(e[u] * inv);
  *(f16x8*)(p + t * 8) = o;
}

// ---------------------------------------------------------------------------
// Output: out[(b0+bb)][s][e] = sum_j P[bb][s][j] * Vt[b0+bb][e][j]
// grid (4, 8, c), 256x256 tiles, K = SS = 2048.
// ---------------------------------------------------------------------------
__global__ __launch_bounds__(512, 2) void pv_gemm(
    const f16* __restrict__ P, const f16* __restrict__ Vt, float* __restrict__ out,
    int b0)
{
  __shared__ alignas(16) f16 As[4 * T32];
  __shared__ alignas(16) f16 Bs[4 * T32];

  const dim3 bid = xcd_swz();
  const int bb = bid.z;
  const int t = threadIdx.x, lane = t & 63, wave = t >> 6;
  const int wm = wave >> 2, wn = wave & 3, col16 = lane & 15, quad = lane >> 4;
  const int m0 = bid.y * 256;  // s
  const int n0 = bid.x * 256;  // e

  const size_t arow0 = (size_t)bb * SS + m0;         // P rows (pitch SS)
  const size_t brow0 = (size_t)(b0 + bb) * DD + n0;  // Vt rows (pitch SS)

  f32x4 acc[8][4];
#pragma unroll
  for (int i = 0; i < 8; ++i)
#pragma unroll
    for (int j = 0; j < 4; ++j) acc[i][j] = f32x4{0.f, 0.f, 0.f, 0.f};

  mma_pipeline<SS>(P, Vt, SS, SS, arow0, brow0,
                   As, Bs, acc, wave, lane, wm, wn, col16, quad);

#pragma unroll
  for (int i = 0; i < 8; ++i)
#pragma unroll
    for (int j = 0; j < 4; ++j)
#pragma unroll
      for (int r = 0; r < 4; ++r) {
        const int gm = m0 + wm * 128 + i * 16 + quad * 4 + r;
        const int gn = n0 + wn * 64 + j * 16 + col16;
        out[((size_t)(b0 + bb) * SS + gm) * DD + gn] = acc[i][j][r];
      }
}

// ---------------------------------------------------------------------------
extern "C" void kernel_launch(void* const* d_in, const int* in_sizes, int n_in,
                              void* d_out, int out_size, void* d_ws, size_t ws_size,
                              hipStream_t stream)
{
  const float* t_out = (const float*)d_in[0];
  const float* c_out = (const float*)d_in[1];
  const float* Wq    = (const float*)d_in[2];
  const float* bq    = (const float*)d_in[3];
  const float* Wk    = (const float*)d_in[4];
  const float* bk    = (const float*)d_in[5];
  const float* Wv    = (const float*)d_in[6];
  const float* bv    = (const float*)d_in[7];
  float* out = (float*)d_out;

  // ---- sizes ----
  const size_t WELT  = (size_t)DD * DD;
  const size_t TD8   = (size_t)BB * SS * DD;             // 16.7M elems
  const size_t XH_B  = TD8 * sizeof(f16);                // 33.55 MB
  const size_t SC1_B = (size_t)SS * SS * sizeof(f16);    // 8.39 MB per batch

  // ---- pick Sc chunk c (pure function of ws_size -> graph-safe) ----
  const size_t FIXED = 3 * WELT * sizeof(f16) + 4 * XH_B;  // 140.5 MB
  int c = 2;
  for (int cand : {8, 4}) {
    size_t xsc = (size_t)cand * SC1_B;
    if (xsc < XH_B) xsc = XH_B;
    if (FIXED + xsc <= ws_size) { c = cand; break; }
  }
  size_t xsc_bytes = (size_t)c * SC1_B;
  if (xsc_bytes < XH_B) xsc_bytes = XH_B;

  // ---- layout: [W][Xh|Sc(alias)][Q][K][Vv][Vt] ----
  char* ws = (char*)d_ws;
  f16* Whq = (f16*)ws;
  f16* Whk = Whq + WELT;
  f16* Whv = Whk + WELT;
  char* XSc = (char*)(Whv + WELT);
  f16* Xh = (f16*)XSc;     // live during prep/proj
  f16* Sc = (f16*)XSc;     // live during attention chunks (aliases Xh)
  f16* Q  = (f16*)(XSc + xsc_bytes);
  f16* K  = Q  + TD8;
  f16* Vv = K  + TD8;
  f16* Vt = Vv + TD8;

  fused_prep<<<dim3(1024 + 16384), dim3(256), 0, stream>>>(
      Wq, Wk, Wv, t_out, c_out, Whq, Whk, Whv, Xh);
  proj_gemm<<<dim3(64, 4, 3), dim3(512), 0, stream>>>(
      Xh, Whq, Whk, Whv, bq, bk, bv, Q, K, Vv);
  transpose_v<<<dim3(32, 16, 8), dim3(256), 0, stream>>>(Vv, Vt);

  for (int b0 = 0; b0 < BB; b0 += c) {
    qk_gemm<<<dim3(8, 8, c), dim3(512), 0, stream>>>(Q, K, Sc, b0);
    softmax_rows<<<dim3(c * SS), dim3(256), 0, stream>>>(Sc);
    pv_gemm<<<dim3(4, 8, c), dim3(512), 0, stream>>>(Sc, Vt, out, b0);
  }
}